// Round 11
// baseline (402.903 us; speedup 1.0000x reference)
//
#include <hip/hip_runtime.h>
#include <math.h>

#define F 128
#define THREEF 384
#define N_RBF 20
#define CUTOFF 5.0f
#define CAP 64
#define TLDS_STRIDE 136   // shorts; 272 B row: 16B-aligned, ~2-way banks (free)
#define CLDS_STRIDE 132   // floats; 528 B row: 16B-aligned, quads alternate banks

typedef __bf16 bf16x8 __attribute__((ext_vector_type(8)));
typedef float  f32x4  __attribute__((ext_vector_type(4)));

// ---------------------------------------------------------------------------
// Prep (fused, block-range sliced):
//   [0,EB)      build: CSR slot via atomic, pack written at (dst,slot)
//   [EB,EB+256) wcast: W1,W2 -> bf16 k-major
//   [EB+256,+8) wrt:   chunked transpose of Wr (layout [(n4*3+c)*128+f][4])
// pack row = {s1, 2cos(x), fcut, ux, uy, uz, src_bits, 0}
// ---------------------------------------------------------------------------
__global__ __launch_bounds__(256) void prep_kernel(
    const float* __restrict__ d_ij, const float* __restrict__ unit_r,
    const int* __restrict__ nbrs,
    const float* __restrict__ W1, const float* __restrict__ W2,
    const float* __restrict__ Wr,
    int* __restrict__ cnt, float* __restrict__ pack,
    __bf16* __restrict__ W1T, __bf16* __restrict__ W2T,
    float* __restrict__ WrT, int E, int EB)
{
    const int tid = threadIdx.x;
    const int b   = blockIdx.x;

    if (b < EB) {                       // ---- build
        const int e = b * 256 + tid;
        if (e >= E) return;
        const int2 nb = ((const int2*)nbrs)[e];
        const int dst = nb.x;
        const int src = nb.y;
        const int slot = atomicAdd(&cnt[dst], 1);
        if (slot >= CAP) return;

        const float d = d_ij[e];
        const float x = (float)M_PI * d * (1.0f / CUTOFF);
        float sx, cx;
        __sincosf(x, &sx, &cx);
        const float fcut = (d < CUTOFF) ? 0.5f * (cx + 1.0f) : 0.0f;
        float4 q0, q1;
        q0.x = sx * fcut / d;           // rbff_1; recurrence keeps fcut/d scale
        q0.y = 2.0f * cx;
        q0.z = fcut;
        q0.w = unit_r[3 * e + 0];
        q1.x = unit_r[3 * e + 1];
        q1.y = unit_r[3 * e + 2];
        q1.z = __int_as_float(src);
        q1.w = 0.0f;
        float4* pk = (float4*)(pack + ((size_t)dst * CAP + slot) * 8);
        pk[0] = q0;
        pk[1] = q1;
    } else if (b < EB + 256) {          // ---- wcast
        const int idx = (b - EB) * 256 + tid;
        if (idx < 128 * 128) {
            const int n = idx >> 7, k = idx & 127;
            W1T[idx] = (__bf16)W1[k * F + n];
        }
        if (idx < 384 * 128) {
            const int n = idx >> 7, k = idx & 127;
            W2T[idx] = (__bf16)W2[k * THREEF + n];
        }
    } else {                            // ---- wrt
        const int idx = (b - EB - 256) * 256 + tid;   // 0..1919
        if (idx >= 5 * 3 * 128) return;
        const int f  = idx & 127;
        const int c  = (idx >> 7) % 3;
        const int n4 = idx / (3 * 128);
        float4 v;
        v.x = Wr[(4 * n4 + 0) * THREEF + c * 128 + f];
        v.y = Wr[(4 * n4 + 1) * THREEF + c * 128 + f];
        v.z = Wr[(4 * n4 + 2) * THREEF + c * 128 + f];
        v.w = Wr[(4 * n4 + 3) * THREEF + c * 128 + f];
        ((float4*)WrT)[idx] = v;
    }
}

// ---------------------------------------------------------------------------
// MLP via bf16 MFMA: phi = silu(h@W1+b1)@W2 + b2, 3 planes [c][node][f].
// One wave per 16 nodes. GEMM2 epilogue staged through LDS -> coalesced
// 512B-row stores (replaces 96 stride-512B scalar dword stores per wave).
// ---------------------------------------------------------------------------
__global__ __launch_bounds__(256) void mlp_mfma_kernel(
    const float* __restrict__ h,      // (N,128) fp32
    const __bf16* __restrict__ W1T,   // (128n,128k)
    const float* __restrict__ b1,     // (128)
    const __bf16* __restrict__ W2T,   // (384n,128k)
    const float* __restrict__ b2,     // (384)
    float* __restrict__ phi, int N)
{
    __shared__ __bf16 t_lds[4][16 * TLDS_STRIDE];   // 17.4 KB
    __shared__ float  c_lds[4][16 * CLDS_STRIDE];   // 33.8 KB

    const int wave = threadIdx.x >> 6;
    const int lane = threadIdx.x & 63;
    const int m    = lane & 15;
    const int quad = lane >> 4;
    const int node0 = blockIdx.x * 64 + wave * 16;
    if (node0 >= N) return;

    // ---- A-frags for GEMM1: h rows, fp32 -> bf16 in registers
    bf16x8 a1[4];
    #pragma unroll
    for (int kb = 0; kb < 4; ++kb) {
        const float* hp = h + (size_t)(node0 + m) * F + kb * 32 + quad * 8;
        const float4 x0 = *(const float4*)hp;
        const float4 x1 = *(const float4*)(hp + 4);
        bf16x8 a;
        a[0] = (__bf16)x0.x; a[1] = (__bf16)x0.y;
        a[2] = (__bf16)x0.z; a[3] = (__bf16)x0.w;
        a[4] = (__bf16)x1.x; a[5] = (__bf16)x1.y;
        a[6] = (__bf16)x1.z; a[7] = (__bf16)x1.w;
        a1[kb] = a;
    }

    // ---- GEMM1 + silu -> t_lds (bf16)
    #pragma unroll
    for (int ct = 0; ct < 8; ++ct) {
        f32x4 acc = {0.0f, 0.0f, 0.0f, 0.0f};
        #pragma unroll
        for (int kb = 0; kb < 4; ++kb) {
            const bf16x8 b =
                *(const bf16x8*)(W1T + (size_t)(ct * 16 + m) * F + kb * 32 + quad * 8);
            acc = __builtin_amdgcn_mfma_f32_16x16x32_bf16(a1[kb], b, acc, 0, 0, 0);
        }
        const int col = ct * 16 + m;
        const float bb = b1[col];
        #pragma unroll
        for (int reg = 0; reg < 4; ++reg) {
            const float x = acc[reg] + bb;
            const float s = x / (1.0f + __expf(-x));
            t_lds[wave][(quad * 4 + reg) * TLDS_STRIDE + col] = (__bf16)s;
        }
    }

    // ---- A-frags for GEMM2 (same-wave LDS, compiler inserts lgkm waits)
    bf16x8 a2[4];
    #pragma unroll
    for (int kb = 0; kb < 4; ++kb)
        a2[kb] = *(const bf16x8*)&t_lds[wave][m * TLDS_STRIDE + kb * 32 + quad * 8];

    // ---- GEMM2 per plane: MFMA -> c_lds -> coalesced row stores
    #pragma unroll
    for (int p = 0; p < 3; ++p) {
        #pragma unroll
        for (int ct = 0; ct < 8; ++ct) {
            f32x4 acc = {0.0f, 0.0f, 0.0f, 0.0f};
            #pragma unroll
            for (int kb = 0; kb < 4; ++kb) {
                const bf16x8 b = *(const bf16x8*)(
                    W2T + (size_t)(p * 128 + ct * 16 + m) * F + kb * 32 + quad * 8);
                acc = __builtin_amdgcn_mfma_f32_16x16x32_bf16(a2[kb], b, acc, 0, 0, 0);
            }
            const int colf = ct * 16 + m;
            const float bb = b2[p * 128 + colf];
            #pragma unroll
            for (int reg = 0; reg < 4; ++reg)
                c_lds[wave][(quad * 4 + reg) * CLDS_STRIDE + colf] = acc[reg] + bb;
        }
        // coalesced store: 16 rows x 128 floats; lanes cover 2 rows per u
        float* pp = phi + (size_t)p * N * F;
        #pragma unroll
        for (int u = 0; u < 8; ++u) {
            const int flat = u * 64 + lane;     // 0..511
            const int row  = flat >> 5;
            const int c4   = flat & 31;
            const float4 val =
                *(const float4*)&c_lds[wave][row * CLDS_STRIDE + c4 * 4];
            *(float4*)&pp[(size_t)(node0 + row) * F + c4 * 4] = val;
        }
    }
}

// ---------------------------------------------------------------------------
// Gather: 1 node x 384 threads; group g = plane c (wave-aligned). Each thread
// owns 20 weights (5 float4, register-resident) instead of 60 -> hoisted out
// of the edge loop. dv = g0(u-terms) + g1(v-terms) combined via LDS.
// ---------------------------------------------------------------------------
__global__ __launch_bounds__(384) void gather_kernel(
    const float* __restrict__ phi,       // 3 planes of (N,128)
    const float* __restrict__ v_i,       // (N,128,3)
    const float* __restrict__ WrT,       // [(n4*3+c)*128+f] float4
    const float* __restrict__ br,        // (384)
    const int*   __restrict__ cnt,       // (N)
    const float* __restrict__ pack,      // (N,CAP,8)
    float* __restrict__ dh,              // (N,128)
    float* __restrict__ dv,              // (N,128,3)
    int N)
{
    __shared__ float4 s_pack[CAP * 2];   // 2 KB
    __shared__ float  s_dv[3][128];      // 1.5 KB

    const int tid  = threadIdx.x;
    const int g    = tid >> 7;           // plane 0,1,2 (2 waves each)
    const int f    = tid & 127;
    const int node = blockIdx.x;

    const int deg0 = cnt[node];
    const int deg  = deg0 < CAP ? deg0 : CAP;

    if (tid < 2 * deg)
        s_pack[tid] = ((const float4*)(pack + (size_t)node * CAP * 8))[tid];
    __syncthreads();

    const float brg = br[g * 128 + f];

    // 5 float4 = 20 weights, loop-invariant -> register resident
    float4 w[5];
    #pragma unroll
    for (int n4 = 0; n4 < 5; ++n4)
        w[n4] = ((const float4*)WrT)[(n4 * 3 + g) * 128 + f];

    const float* phig = phi + (size_t)g * N * F;

    float acc0 = 0.0f, acc1 = 0.0f, acc2 = 0.0f;   // g0/g1: dv partials, g2: dh in acc0

    for (int i = 0; i < deg; ++i) {
        const float* q = (const float*)&s_pack[2 * i];
        const float s1   = q[0];
        const float twoc = q[1];
        const float fcut = q[2];
        const int src = __builtin_amdgcn_readfirstlane(__float_as_int(q[6]));

        float a = brg * fcut;
        float rp = 0.0f, rc = s1;
        #pragma unroll
        for (int n4 = 0; n4 < 5; ++n4) {
            #pragma unroll
            for (int k = 0; k < 4; ++k) {
                a = fmaf(rc, ((const float*)&w[n4])[k], a);
                const float rn = fmaf(twoc, rc, -rp);
                rp = rc;
                rc = rn;
            }
        }

        const float fg = phig[(size_t)src * F + f] * a;

        if (g == 0) {
            acc0 = fmaf(fg, q[3], acc0);     // ux
            acc1 = fmaf(fg, q[4], acc1);     // uy
            acc2 = fmaf(fg, q[5], acc2);     // uz
        } else if (g == 1) {
            const float* vs = v_i + (size_t)src * THREEF + 3 * f;
            acc0 = fmaf(fg, vs[0], acc0);
            acc1 = fmaf(fg, vs[1], acc1);
            acc2 = fmaf(fg, vs[2], acc2);
        } else {
            acc0 += fg;                       // dh
        }
    }

    if (g == 0) {
        s_dv[0][f] = acc0;
        s_dv[1][f] = acc1;
        s_dv[2][f] = acc2;
    }
    __syncthreads();

    if (g == 1) {
        float* dvp = dv + (size_t)node * THREEF + 3 * f;
        dvp[0] = s_dv[0][f] + acc0;
        dvp[1] = s_dv[1][f] + acc1;
        dvp[2] = s_dv[2][f] + acc2;
    } else if (g == 2) {
        dh[(size_t)node * F + f] = acc0;
    }
}

extern "C" void kernel_launch(void* const* d_in, const int* in_sizes, int n_in,
                              void* d_out, int out_size, void* d_ws, size_t ws_size,
                              hipStream_t stream) {
    const float* h_i    = (const float*)d_in[0];
    const float* v_i    = (const float*)d_in[1];
    const float* d_ij   = (const float*)d_in[2];
    const float* unit_r = (const float*)d_in[3];
    const int*   nbrs   = (const int*)  d_in[4];
    const float* W1     = (const float*)d_in[5];
    const float* b1     = (const float*)d_in[6];
    const float* W2     = (const float*)d_in[7];
    const float* b2     = (const float*)d_in[8];
    const float* Wr     = (const float*)d_in[9];
    const float* br     = (const float*)d_in[10];

    const int N = in_sizes[0] / F;       // 20000
    const int E = in_sizes[2];           // 320000

    float* dh = (float*)d_out;              // (N,128)
    float* dv = dh + (size_t)N * F;         // (N,128,3)

    // workspace: phi (3NF) | pack (N*CAP*8) | WrT | cnt | W1T | W2T
    float*  phi  = (float*)d_ws;                           // 30.7 MB
    float*  pack = phi + (size_t)3 * N * F;                // 41 MB
    float*  WrT  = pack + (size_t)N * CAP * 8;             // 30 KB
    int*    cnt  = (int*)(WrT + 5 * 3 * 128 * 4);          // 80 KB
    __bf16* W1T  = (__bf16*)(cnt + N);                     // 32 KB
    __bf16* W2T  = W1T + 128 * 128;                        // 96 KB

    const int EB = (E + 255) / 256;      // 1250 build blocks

    hipMemsetAsync(cnt, 0, (size_t)N * sizeof(int), stream);

    prep_kernel<<<EB + 256 + 8, 256, 0, stream>>>(
        d_ij, unit_r, nbrs, W1, W2, Wr, cnt, pack, W1T, W2T, WrT, E, EB);
    mlp_mfma_kernel<<<(N + 63) / 64, 256, 0, stream>>>(h_i, W1T, b1, W2T, b2,
                                                       phi, N);
    gather_kernel<<<N, 384, 0, stream>>>(phi, v_i, WrT, br, cnt, pack,
                                         dh, dv, N);
}